// Round 3
// baseline (271.624 us; speedup 1.0000x reference)
//
#include <hip/hip_runtime.h>

namespace {
constexpr int S_LEN = 512;
constexpr int BATCH = 1024;
constexpr int TAG = 64;
constexpr int START_IDX = 0;
constexpr int END_IDX = 1;
constexpr float NEG_INF = -10000.0f;
constexpr int CHUNK = 64;              // steps per LDS chunk (16 KB)
constexpr float LN2F = 0.69314718055994530942f;

typedef float v2f __attribute__((ext_vector_type(2)));
typedef float v4f __attribute__((ext_vector_type(4)));

typedef const __attribute__((address_space(1))) void* gas_ptr;
typedef __attribute__((address_space(3))) void* las_ptr;

__device__ inline void gld_lds16(const float* g, float* l) {
  // LDS dest = wave-uniform base + lane*16 (hardware); global src is per-lane.
  __builtin_amdgcn_global_load_lds((gas_ptr)(const void*)g, (las_ptr)(void*)l, 16, 0, 0);
}
}

// One wave (64 lanes) per batch; lane = destination tag j.
// Linear-domain recurrence: p_j = exp(alpha_j - etot*ln2), renormalized each step by
// an exact power of 2 from the exponent bits of lane 2's p.
//   t_j  = sum_i E[j,i] * p_i
// The p broadcast goes through v_readlane -> SGPR -> v_fmac scalar operand: the
// serial chain contains ONLY VALU issue (no LDS round-trip, no barriers, no waitcnt).
// Feats are staged 64 steps ahead into double-buffered LDS (global_load_lds) and
// pulled 8 steps ahead into registers; exp(feat) is precomputed off-chain.
__global__ __launch_bounds__(64, 1) void crf_fwd_kernel(
    const float* __restrict__ feats,   // [S, B, T]
    const float* __restrict__ mask,    // [S, B]
    const float* __restrict__ trans,   // [T, T]
    float* __restrict__ out) {         // [B]
  const int b = blockIdx.x;
  const int lane = threadIdx.x;  // tag j

  __shared__ __align__(16) float fchunk[2][CHUNK * TAG];  // 2 x 16 KB

  // ---- effective length L = sum_s mask[s,b] (mask monotone non-increasing) ----
  int L;
  {
    float sum = 0.0f;
#pragma unroll
    for (int k = 0; k < S_LEN / 64; ++k) sum += mask[(size_t)(lane + 64 * k) * BATCH + b];
#pragma unroll
    for (int off = 32; off >= 1; off >>= 1) sum += __shfl_xor(sum, off, 64);
    L = (int)(sum + 0.5f);
  }

  // ---- one-time: E row j as 64 scalar registers (exp of transition row) ----
  float Ee[TAG];
  {
    const float* row = trans + lane * TAG;
#pragma unroll
    for (int k = 0; k < TAG / 4; ++k) {
      v4f tv;
      __builtin_memcpy(&tv, row + 4 * k, sizeof(v4f));
      Ee[4 * k + 0] = __expf(tv.x);  // exp(-10000) -> 0, no NaN
      Ee[4 * k + 1] = __expf(tv.y);
      Ee[4 * k + 2] = __expf(tv.z);
      Ee[4 * k + 3] = __expf(tv.w);
    }
  }

  // per-lane invariant pieces of the staging address:
  // one gld_lds16 moves 4 rows (4 x 256 B): lane l -> row l>>4, col (l&15)*4
  const float* gstage0 =
      feats + ((size_t)(lane >> 4) * BATCH + b) * TAG + ((lane & 15) << 2);

  auto stage_chunk = [&](int base_s, int nb) {
    const float* g0 = gstage0 + (size_t)base_s * (BATCH * TAG);
#pragma unroll
    for (int q = 0; q < 16; ++q) {
      gld_lds16(g0 + (size_t)(4 * q) * (BATCH * TAG), &fchunk[nb][q * 256]);
    }
  };

  float p = (lane == START_IDX) ? 1.0f : 0.0f;
  int etot = 0;  // running power-of-2 count: M = etot * ln2 (exact scaling)

  // ---- prologue: stage chunk 0 and wait for it ----
  stage_chunk(0, 0);
  asm volatile("s_waitcnt vmcnt(0)" ::: "memory");
  __builtin_amdgcn_sched_barrier(0);
  __builtin_amdgcn_wave_barrier();

  // one step: chain = 64 readlane + 64 fmac + 7-add tree + 1 mul (pure VALU issue)
  auto step = [&](float ex) {
    const unsigned pu = __float_as_uint(p);

    // anchor renorm (SALU/uniform; overlaps the fmac stream)
    const unsigned pb = __builtin_amdgcn_readlane(pu, 2);
    const unsigned eb = (pb == 0u) ? 127u : (pb >> 23);
    etot += (int)eb - 127;
    const float scale = __uint_as_float((254u - eb) << 23);  // 2^(127-eb), exact
    const float cg = ex * scale;

    float a0 = 0.f, a1 = 0.f, a2 = 0.f, a3 = 0.f;
    float a4 = 0.f, a5 = 0.f, a6 = 0.f, a7 = 0.f;
#pragma unroll
    for (int k = 0; k < TAG; k += 8) {
      a0 = __builtin_fmaf(__uint_as_float(__builtin_amdgcn_readlane(pu, k + 0)), Ee[k + 0], a0);
      a1 = __builtin_fmaf(__uint_as_float(__builtin_amdgcn_readlane(pu, k + 1)), Ee[k + 1], a1);
      a2 = __builtin_fmaf(__uint_as_float(__builtin_amdgcn_readlane(pu, k + 2)), Ee[k + 2], a2);
      a3 = __builtin_fmaf(__uint_as_float(__builtin_amdgcn_readlane(pu, k + 3)), Ee[k + 3], a3);
      a4 = __builtin_fmaf(__uint_as_float(__builtin_amdgcn_readlane(pu, k + 4)), Ee[k + 4], a4);
      a5 = __builtin_fmaf(__uint_as_float(__builtin_amdgcn_readlane(pu, k + 5)), Ee[k + 5], a5);
      a6 = __builtin_fmaf(__uint_as_float(__builtin_amdgcn_readlane(pu, k + 6)), Ee[k + 6], a6);
      a7 = __builtin_fmaf(__uint_as_float(__builtin_amdgcn_readlane(pu, k + 7)), Ee[k + 7], a7);
    }
    const float t = ((a0 + a1) + (a2 + a3)) + ((a4 + a5) + (a6 + a7));
    p = t * cg;  // single on-chain multiply
  };

  for (int c = 0;; ++c) {
    const int base = c * CHUNK;
    int n = L - base;
    if (n <= 0) break;
    if (n > CHUNK) n = CHUNK;

    const int nbase = base + CHUNK;
    if (nbase < S_LEN) stage_chunk(nbase, (c + 1) & 1);  // async, 64 steps ahead

    const float* fb = &fchunk[c & 1][0];

    // 8-step groups: feat reads + exp batched off-chain
    auto group8 = [&](int s0) {
      float ex[8];
#pragma unroll
      for (int i = 0; i < 8; ++i) ex[i] = fb[(s0 + i) * TAG + lane];
#pragma unroll
      for (int i = 0; i < 8; ++i) ex[i] = __expf(ex[i]);
#pragma unroll
      for (int i = 0; i < 8; ++i) step(ex[i]);
    };

    if (n == CHUNK) {
      for (int g = 0; g < CHUNK / 8; ++g) group8(8 * g);
    } else {
      const int full = n >> 3;
      for (int g = 0; g < full; ++g) group8(8 * g);
      for (int i = full * 8; i < n; ++i) {  // tail (rare): on-chain exp is fine here
        step(__expf(fb[i * TAG + lane]));
      }
      break;  // L reached inside this chunk
    }

    if (nbase >= L) break;  // done; skip the drain

    // next chunk's loads were issued 64 steps ago: drain is ~free
    asm volatile("s_waitcnt vmcnt(0)" ::: "memory");
    __builtin_amdgcn_sched_barrier(0);
    __builtin_amdgcn_wave_barrier();
  }

  // drain any in-flight staging before LDS is deallocated at wave exit
  asm volatile("s_waitcnt vmcnt(0)" ::: "memory");

  // ---- epilogue: out[b] = logsumexp_j(etot*ln2 + log p_j + trans[END, j]) ----
  {
    const float a = (float)etot * LN2F + __logf(p) + trans[END_IDX * TAG + lane];
    float mx = a;  // p==0 -> a=-inf; lane 2 always finite so mx finite
#pragma unroll
    for (int off = 32; off >= 1; off >>= 1) mx = fmaxf(mx, __shfl_xor(mx, off, 64));
    float e = __expf(a - mx);
#pragma unroll
    for (int off = 32; off >= 1; off >>= 1) e += __shfl_xor(e, off, 64);
    if (lane == 0) out[b] = mx + __logf(e);
  }
}

extern "C" void kernel_launch(void* const* d_in, const int* in_sizes, int n_in,
                              void* d_out, int out_size, void* d_ws, size_t ws_size,
                              hipStream_t stream) {
  const float* feats = (const float*)d_in[0];
  const float* mask = (const float*)d_in[1];
  const float* trans = (const float*)d_in[2];
  float* out = (float*)d_out;
  crf_fwd_kernel<<<dim3(BATCH), dim3(64), 0, stream>>>(feats, mask, trans, out);
}